// Round 10
// baseline (205.391 us; speedup 1.0000x reference)
//
#include <hip/hip_runtime.h>
#include <math.h>

#define N_NODES 50000
#define D 128
#define NE 800000
#define BN 64                  // nodes per partition bucket (dst >> 6)
#define NBUCK 782              // ceil(N_NODES / 64)
#define CAP 1280               // records per bucket (mean 1024, 8 sigma)
#define HB 32                  // nodes per fused block (half bucket)
#define NHALF 1564             // 2 * NBUCK
#define CAP_H 704              // list-array bound per type per half bucket
#define EPB 4096               // edges per partition block
#define PBLK 196               // ceil(NE / EPB)
#define F2B_BLKS 6250          // N*D/4 / 256
#define WPREP_BLKS 384         // 2*12*128*32 / 256
#define MPITCH 68              // uint pitch for LDS mean rows

typedef unsigned int uint;
typedef unsigned short ushort;

using bf16x8 = __attribute__((ext_vector_type(8))) short;
using f32x4  = __attribute__((ext_vector_type(4))) float;

// ---- bf16 helpers (bit-level, RN-even) ----
__device__ __forceinline__ float bflo(uint w) {
    union { uint u; float f; } c; c.u = w << 16; return c.f;
}
__device__ __forceinline__ float bfhi(uint w) {
    union { uint u; float f; } c; c.u = w & 0xffff0000u; return c.f;
}
__device__ __forceinline__ uint fp2bf_rn(float f) {
    union { float f; uint u; } c; c.f = f;
    return (c.u + 0x7fffu + ((c.u >> 16) & 1u)) >> 16;
}

// ---------------------------------------------------------------------------
// build: [0, 2*PBLK) edge partition into 64-node bucket record runs;
//        then x -> bf16; then W pre-pack.
// rec = src | (dst&63)<<17.  After this kernel bcur[b] = bucket record count.
// ---------------------------------------------------------------------------
__global__ __launch_bounds__(256) void build_kernel(
    const float4* __restrict__ x4, uint2* __restrict__ featb2,
    const float* __restrict__ Wl, const float* __restrict__ Wr,
    ushort* __restrict__ Wpack,
    const int* __restrict__ srcA, const int* __restrict__ dstA,
    const int* __restrict__ srcB, const int* __restrict__ dstB,
    int* __restrict__ bcurA, int* __restrict__ bcurB,
    uint* __restrict__ ebufA, uint* __restrict__ ebufB) {
    const int blk = blockIdx.x;
    const int t   = threadIdx.x;
    if (blk < 2 * PBLK) {
        __shared__ int h[NBUCK];
        __shared__ int base[NBUCK];
        const int typ = blk >= PBLK;
        const int* src = typ ? srcB : srcA;
        const int* dst = typ ? dstB : dstA;
        int* bc        = typ ? bcurB : bcurA;
        uint* ebuf     = typ ? ebufB : ebufA;
        const int e0 = (blk - (typ ? PBLK : 0)) * EPB;
        for (int j = t; j < NBUCK; j += 256) h[j] = 0;
        __syncthreads();
#pragma unroll
        for (int i = 0; i < EPB / 256; ++i) {
            const int e = e0 + t + i * 256;
            if (e < NE) atomicAdd(&h[dst[e] >> 6], 1);
        }
        __syncthreads();
        for (int j = t; j < NBUCK; j += 256) {
            const int c = h[j];
            base[j] = c ? atomicAdd(&bc[j], c) : 0;
            h[j] = 0;                    // reuse as local cursor
        }
        __syncthreads();
#pragma unroll
        for (int i = 0; i < EPB / 256; ++i) {
            const int e = e0 + t + i * 256;
            if (e < NE) {
                const int d  = dst[e];
                const int bk = d >> 6;
                const int pos = atomicAdd(&h[bk], 1);
                const int off = base[bk] + pos;
                if (off < CAP)
                    ebuf[(size_t)bk * CAP + off] = (uint)src[e] | ((uint)(d & 63) << 17);
            }
        }
    } else if (blk < 2 * PBLK + F2B_BLKS) {
        const int i = (blk - 2 * PBLK) * 256 + t;
        float4 v = x4[i];
        uint2 o;
        o.x = fp2bf_rn(v.x) | (fp2bf_rn(v.y) << 16);
        o.y = fp2bf_rn(v.z) | (fp2bf_rn(v.w) << 16);
        featb2[i] = o;
    } else {
        const int i   = (blk - 2 * PBLK - F2B_BLKS) * 256 + t;  // [2][12][128][32]
        const int l   = i / 49152;
        const int rem = i % 49152;
        const int ks  = rem / 4096;
        const int n   = (rem % 4096) / 32;
        const int kk  = rem % 32;
        const int r   = ks * 32 + kk;
        float v;
        if (r < 128)       v = Wl[(((size_t)l * 2 + 0) * 128 + r) * 128 + n];
        else if (r < 256)  v = Wl[(((size_t)l * 2 + 1) * 128 + (r - 128)) * 128 + n];
        else               v = Wr[(((size_t)l * 2 + 0) * 128 + (r - 256)) * 128 + n]
                             + Wr[(((size_t)l * 2 + 1) * 128 + (r - 256)) * 128 + n];
        Wpack[i] = (ushort)fp2bf_rn(v);
    }
}

// ---------------------------------------------------------------------------
// fused: one block per 32-node HALF-bucket (grid 1564 x 1024 thr = 3.05
// occupancy-rounds at 2 blocks/CU -> mean2-like packing):
//  (1) filter+sort parent bucket's records into 64 per-(node,type) lists
//  (2) gather: 64 clusters x 16 lanes, ONE list each, register accumulation
//  (3) 32x128 MFMA GEMM over K=384 = [meanA|meanB|self]
//      out[i,:] = act( meanA@W0 + meanB@W1 + self@(Wr0+Wr1) + b0+b1 )
// ---------------------------------------------------------------------------
__global__ __launch_bounds__(1024, 8) void fused_kernel(
    const uint4* __restrict__ feat,      // layer input, bf16 [N][16]
    const uint* __restrict__ ebufA, const uint* __restrict__ ebufB,
    const int* __restrict__ bcntA, const int* __restrict__ bcntB,
    const ushort* __restrict__ Wpack,    // [12][128][32] bf16 for this layer
    const float* __restrict__ bias0, const float* __restrict__ bias1,
    float* __restrict__ outf, ushort* __restrict__ outb, int act) {

    __shared__ uint   mlds[2 * HB * MPITCH];   // bf16 means  (17408 B)
    __shared__ ushort lidx[2][CAP_H];          // per-(node,type) lists (2816 B)
    __shared__ int    cnt[64], ex[64], cur[64];

    const int bq = blockIdx.x;
    const int b  = bq >> 1;          // parent 64-node bucket
    const int q  = bq & 1;           // which half
    const int t  = threadIdx.x;

    // ---- (1) filter + in-LDS sort into per-node lists ----
    if (t < 64) cnt[t] = 0;
    __syncthreads();
    int countA = bcntA[b]; if (countA > CAP) countA = CAP;
    int countB = bcntB[b]; if (countB > CAP) countB = CAP;
    const uint* ebA = ebufA + (size_t)b * CAP;
    const uint* ebB = ebufB + (size_t)b * CAP;
    for (int e = t; e < countA; e += 1024) {
        const uint rec = ebA[e];
        if ((int)((rec >> 17) >> 5) == q) atomicAdd(&cnt[(rec >> 17) & 31], 1);
    }
    for (int e = t; e < countB; e += 1024) {
        const uint rec = ebB[e];
        if ((int)((rec >> 17) >> 5) == q) atomicAdd(&cnt[32 + ((rec >> 17) & 31)], 1);
    }
    __syncthreads();
    if (t < 64) ex[t] = cnt[t];
    __syncthreads();
    // two independent 32-wide Hillis-Steele scans (per type)
    for (int off = 1; off < 32; off <<= 1) {
        int v = 0;
        if (t < 64 && (t & 31) >= off) v = ex[t - off];
        __syncthreads();
        if (t < 64 && (t & 31) >= off) ex[t] += v;
        __syncthreads();
    }
    if (t < 64) { ex[t] -= cnt[t]; cur[t] = ex[t]; }     // exclusive base
    __syncthreads();
    for (int e = t; e < countA; e += 1024) {
        const uint rec = ebA[e];
        if ((int)((rec >> 17) >> 5) == q) {
            const int p = atomicAdd(&cur[(rec >> 17) & 31], 1);
            if (p < CAP_H) lidx[0][p] = (ushort)(rec & 0x1FFFFu);
        }
    }
    for (int e = t; e < countB; e += 1024) {
        const uint rec = ebB[e];
        if ((int)((rec >> 17) >> 5) == q) {
            const int p = atomicAdd(&cur[32 + ((rec >> 17) & 31)], 1);
            if (p < CAP_H) lidx[1][p] = (ushort)(rec & 0x1FFFFu);
        }
    }
    __syncthreads();

    // ---- (2) gather: 64 clusters, one (node,type) list each ----
    const int cl = t >> 4, ln = t & 15;
    {
        const int typ   = cl >> 5;
        const int lnode = cl & 31;
        const int beg   = ex[typ * 32 + lnode];
        const int deg   = cnt[typ * 32 + lnode];
        int fin = beg + deg; if (fin > CAP_H) fin = CAP_H;
        const ushort* lx = lidx[typ];
        float a[8] = {0.f,0.f,0.f,0.f,0.f,0.f,0.f,0.f};
#define ACC(v) { a[0]+=bflo(v.x); a[1]+=bfhi(v.x); a[2]+=bflo(v.y); a[3]+=bfhi(v.y); \
                 a[4]+=bflo(v.z); a[5]+=bfhi(v.z); a[6]+=bflo(v.w); a[7]+=bfhi(v.w); }
        int e = beg;
        for (; e + 4 <= fin; e += 4) {
            uint4 v0 = feat[(size_t)lx[e]     * 16 + ln];
            uint4 v1 = feat[(size_t)lx[e + 1] * 16 + ln];
            uint4 v2 = feat[(size_t)lx[e + 2] * 16 + ln];
            uint4 v3 = feat[(size_t)lx[e + 3] * 16 + ln];
            ACC(v0); ACC(v1); ACC(v2); ACC(v3);
        }
        for (; e < fin; ++e) {
            uint4 v0 = feat[(size_t)lx[e] * 16 + ln];
            ACC(v0);
        }
#undef ACC
        const float invd = 1.0f / fmaxf((float)deg, 1.0f);
        uint4 o;
        o.x = fp2bf_rn(a[0] * invd) | (fp2bf_rn(a[1] * invd) << 16);
        o.y = fp2bf_rn(a[2] * invd) | (fp2bf_rn(a[3] * invd) << 16);
        o.z = fp2bf_rn(a[4] * invd) | (fp2bf_rn(a[5] * invd) << 16);
        o.w = fp2bf_rn(a[6] * invd) | (fp2bf_rn(a[7] * invd) << 16);
        *reinterpret_cast<uint4*>(&mlds[(typ * HB + cl % 32) * MPITCH + ln * 4]) = o;
    }
    __syncthreads();

    // ---- (3) GEMM: 32 rows x 128 cols, K = 12 x 32; wave = one 16x16 C-tile ----
    const int wid = t >> 6, wl = t & 63;
    const int mrow = wl & 15, g = wl >> 4;
    const int mt = wid >> 3;               // 0..1
    const int nf = wid & 7;                // 0..7
    const int arow = mt * 16 + mrow;       // 0..31

    f32x4 acc = (f32x4){0.f, 0.f, 0.f, 0.f};
#pragma unroll
    for (int ks = 0; ks < 12; ++ks) {
        union { uint4 u; bf16x8 v; } av;
        if (ks < 8) {
            av.u = *reinterpret_cast<const uint4*>(
                &mlds[((ks >> 2) * HB + arow) * MPITCH + (ks & 3) * 16 + g * 4]);
        } else {
            int srow = bq * HB + arow;
            if (srow >= N_NODES) srow = N_NODES - 1;
            av.u = feat[(size_t)srow * 16 + (ks & 3) * 4 + g];
        }
        union { uint4 u; bf16x8 v; } bv;
        bv.u = *reinterpret_cast<const uint4*>(
            Wpack + (size_t)ks * 4096 + ((nf * 16 + mrow) * 32 + g * 8));
        acc = __builtin_amdgcn_mfma_f32_16x16x32_bf16(av.v, bv.v, acc, 0, 0, 0);
    }

    // ---- epilogue ----
    {
        const int col = nf * 16 + mrow;
        const float bias = bias0[col] + bias1[col];
#pragma unroll
        for (int r = 0; r < 4; ++r) {
            const int row = bq * HB + mt * 16 + g * 4 + r;
            if (row < N_NODES) {
                const float v = acc[r] + bias;
                if (act) outf[(size_t)row * D + col] = 1.0f / (1.0f + expf(-v));
                else     outb[(size_t)row * D + col] = (ushort)fp2bf_rn(v);
            }
        }
    }
}

// ---------------------------------------------------------------------------
extern "C" void kernel_launch(void* const* d_in, const int* in_sizes, int n_in,
                              void* d_out, int out_size, void* d_ws, size_t ws_size,
                              hipStream_t stream) {
    const float* x    = (const float*)d_in[0];
    const int*   ei_a = (const int*)d_in[2];
    const int*   ei_b = (const int*)d_in[3];
    const float* Wl   = (const float*)d_in[4];
    const float* bl   = (const float*)d_in[5];
    const float* Wr   = (const float*)d_in[6];
    float* out = (float*)d_out;

    // ---- workspace (~33.8 MB) ----
    ushort* featb = (ushort*)d_ws;                           // [N][128]
    ushort* feat2 = featb + (size_t)N_NODES * D;             // [N][128]
    uint* ebufA = (uint*)(feat2 + (size_t)N_NODES * D);      // NBUCK*CAP
    uint* ebufB = ebufA + (size_t)NBUCK * CAP;
    int* bcurA  = (int*)(ebufB + (size_t)NBUCK * CAP);       // NBUCK
    int* bcurB  = bcurA + NBUCK;
    ushort* Wpack = (ushort*)(((size_t)(bcurB + NBUCK) + 63) & ~(size_t)63);

    const int* srcA = ei_a;
    const int* dstA = ei_a + NE;
    const int* srcB = ei_b;
    const int* dstB = ei_b + NE;

    hipMemsetAsync(bcurA, 0, 2ull * NBUCK * sizeof(int), stream);
    build_kernel<<<2 * PBLK + F2B_BLKS + WPREP_BLKS, 256, 0, stream>>>(
        (const float4*)x, (uint2*)featb, Wl, Wr, Wpack,
        srcA, dstA, srcB, dstB, bcurA, bcurB, ebufA, ebufB);

    fused_kernel<<<NHALF, 1024, 0, stream>>>(
        (const uint4*)featb, ebufA, ebufB, bcurA, bcurB,
        Wpack, bl + 0 * D, bl + 1 * D, nullptr, feat2, 0);
    fused_kernel<<<NHALF, 1024, 0, stream>>>(
        (const uint4*)feat2, ebufA, ebufB, bcurA, bcurB,
        Wpack + (size_t)12 * 128 * 32, bl + 2 * D, bl + 3 * D, out, nullptr, 1);
}

// Round 12
// 177.772 us; speedup vs baseline: 1.1554x; 1.1554x over previous
//
#include <hip/hip_runtime.h>
#include <math.h>

#define N_NODES 50000
#define D 128
#define NE 800000
#define BN 64                  // nodes per bucket (dst >> 6)
#define NBUCK 782              // ceil(N_NODES / 64)
#define CAP 1280               // records per bucket (mean 1024, 8 sigma)
#define EPB 4096               // edges per partition block
#define PBLK 196               // ceil(NE / EPB)
#define F2B_BLKS 6250          // N*D/4 / 256
#define WPREP_BLKS 384         // 2*12*128*32 / 256
#define MPITCH 68              // uint pitch for LDS mean rows

typedef unsigned int uint;
typedef unsigned short ushort;
typedef unsigned char uchar;

using bf16x8 = __attribute__((ext_vector_type(8))) short;
using f32x4  = __attribute__((ext_vector_type(4))) float;

// ---- bf16 helpers (bit-level, RN-even) ----
__device__ __forceinline__ float bflo(uint w) {
    union { uint u; float f; } c; c.u = w << 16; return c.f;
}
__device__ __forceinline__ float bfhi(uint w) {
    union { uint u; float f; } c; c.u = w & 0xffff0000u; return c.f;
}
__device__ __forceinline__ uint fp2bf_rn(float f) {
    union { float f; uint u; } c; c.f = f;
    return (c.u + 0x7fffu + ((c.u >> 16) & 1u)) >> 16;
}

// ---------------------------------------------------------------------------
// build: [0, 2*PBLK) edge partition into 64-node bucket record runs;
//        then x -> bf16 + fp8; then W pre-pack.
// rec = src | (dst&63)<<17.  After this kernel bcur[b] = bucket record count.
// ---------------------------------------------------------------------------
__global__ __launch_bounds__(256) void build_kernel(
    const float4* __restrict__ x4, uint2* __restrict__ featb2,
    uint* __restrict__ feat8w,
    const float* __restrict__ Wl, const float* __restrict__ Wr,
    ushort* __restrict__ Wpack,
    const int* __restrict__ srcA, const int* __restrict__ dstA,
    const int* __restrict__ srcB, const int* __restrict__ dstB,
    int* __restrict__ bcurA, int* __restrict__ bcurB,
    uint* __restrict__ ebufA, uint* __restrict__ ebufB) {
    const int blk = blockIdx.x;
    const int t   = threadIdx.x;
    if (blk < 2 * PBLK) {
        __shared__ int h[NBUCK];
        __shared__ int base[NBUCK];
        const int typ = blk >= PBLK;
        const int* src = typ ? srcB : srcA;
        const int* dst = typ ? dstB : dstA;
        int* bc        = typ ? bcurB : bcurA;
        uint* ebuf     = typ ? ebufB : ebufA;
        const int e0 = (blk - (typ ? PBLK : 0)) * EPB;
        for (int j = t; j < NBUCK; j += 256) h[j] = 0;
        __syncthreads();
#pragma unroll
        for (int i = 0; i < EPB / 256; ++i) {
            const int e = e0 + t + i * 256;
            if (e < NE) atomicAdd(&h[dst[e] >> 6], 1);
        }
        __syncthreads();
        for (int j = t; j < NBUCK; j += 256) {
            const int c = h[j];
            base[j] = c ? atomicAdd(&bc[j], c) : 0;
            h[j] = 0;                    // reuse as local cursor
        }
        __syncthreads();
#pragma unroll
        for (int i = 0; i < EPB / 256; ++i) {
            const int e = e0 + t + i * 256;
            if (e < NE) {
                const int d  = dst[e];
                const int bk = d >> 6;
                const int pos = atomicAdd(&h[bk], 1);
                const int off = base[bk] + pos;
                if (off < CAP)
                    ebuf[(size_t)bk * CAP + off] = (uint)src[e] | ((uint)(d & 63) << 17);
            }
        }
    } else if (blk < 2 * PBLK + F2B_BLKS) {
        const int i = (blk - 2 * PBLK) * 256 + t;
        float4 v = x4[i];
        uint2 o;
        o.x = fp2bf_rn(v.x) | (fp2bf_rn(v.y) << 16);
        o.y = fp2bf_rn(v.z) | (fp2bf_rn(v.w) << 16);
        featb2[i] = o;
        int pk = __builtin_amdgcn_cvt_pk_fp8_f32(v.x, v.y, 0, false);
        pk = __builtin_amdgcn_cvt_pk_fp8_f32(v.z, v.w, pk, true);
        feat8w[i] = (uint)pk;
    } else {
        const int i   = (blk - 2 * PBLK - F2B_BLKS) * 256 + t;  // [2][12][128][32]
        const int l   = i / 49152;
        const int rem = i % 49152;
        const int ks  = rem / 4096;
        const int n   = (rem % 4096) / 32;
        const int kk  = rem % 32;
        const int r   = ks * 32 + kk;
        float v;
        if (r < 128)       v = Wl[(((size_t)l * 2 + 0) * 128 + r) * 128 + n];
        else if (r < 256)  v = Wl[(((size_t)l * 2 + 1) * 128 + (r - 128)) * 128 + n];
        else               v = Wr[(((size_t)l * 2 + 0) * 128 + (r - 256)) * 128 + n]
                             + Wr[(((size_t)l * 2 + 1) * 128 + (r - 256)) * 128 + n];
        Wpack[i] = (ushort)fp2bf_rn(v);
    }
}

// ---------------------------------------------------------------------------
// fused: one block per 64-node bucket:
//  (1) in-LDS sort of bucket records into 128 per-(node,type) lists
//  (2) gather means from the FP8 feature copy (128B rows = 2 cache lines),
//      register accumulation, bf16 means -> LDS
//  (3) 64x128 MFMA GEMM over K=384 = [meanA|meanB|self] (bf16 inputs)
//      out[i,:] = act( meanA@W0 + meanB@W1 + self@(Wr0+Wr1) + b0+b1 )
// 1024 threads = 16 waves; 64 gather clusters x 16 lanes.
// ---------------------------------------------------------------------------
__global__ __launch_bounds__(1024, 8) void fused_kernel(
    const uint4* __restrict__ feat,      // layer input bf16 [N][16] (self/GEMM)
    const uint2* __restrict__ feat8,     // layer input fp8 [N][16] (gather)
    const uint* __restrict__ ebufA, const uint* __restrict__ ebufB,
    const int* __restrict__ bcntA, const int* __restrict__ bcntB,
    const ushort* __restrict__ Wpack,    // [12][128][32] bf16 for this layer
    const float* __restrict__ bias0, const float* __restrict__ bias1,
    float* __restrict__ outf, ushort* __restrict__ outb,
    uchar* __restrict__ out8, int act) {

    __shared__ uint   mlds[2 * BN * MPITCH];   // bf16 means  (34816 B)
    __shared__ ushort lidx[2][CAP];            // per-node src lists (5120 B)
    __shared__ int    cnt[128], ex[128], cur[128];

    const int b = blockIdx.x;
    const int t = threadIdx.x;

    // ---- (1) in-LDS per-node sort of bucket records ----
    if (t < 128) cnt[t] = 0;
    __syncthreads();
    int countA = bcntA[b]; if (countA > CAP) countA = CAP;
    int countB = bcntB[b]; if (countB > CAP) countB = CAP;
    const uint* ebA = ebufA + (size_t)b * CAP;
    const uint* ebB = ebufB + (size_t)b * CAP;
    for (int e = t; e < countA; e += 1024) atomicAdd(&cnt[ebA[e] >> 17], 1);
    for (int e = t; e < countB; e += 1024) atomicAdd(&cnt[64 + (ebB[e] >> 17)], 1);
    __syncthreads();
    if (t < 128) ex[t] = cnt[t];
    __syncthreads();
    // two independent 64-wide Hillis-Steele scans (threads 0-63 and 64-127)
    for (int off = 1; off < 64; off <<= 1) {
        int v = 0;
        if (t < 128 && (t & 63) >= off) v = ex[t - off];
        __syncthreads();
        if (t < 128 && (t & 63) >= off) ex[t] += v;
        __syncthreads();
    }
    if (t < 128) { ex[t] -= cnt[t]; cur[t] = ex[t]; }   // exclusive base
    __syncthreads();
    for (int e = t; e < countA; e += 1024) {
        const uint rec = ebA[e];
        const int p = atomicAdd(&cur[rec >> 17], 1);
        lidx[0][p] = (ushort)(rec & 0x1FFFFu);
    }
    for (int e = t; e < countB; e += 1024) {
        const uint rec = ebB[e];
        const int p = atomicAdd(&cur[64 + (rec >> 17)], 1);
        lidx[1][p] = (ushort)(rec & 0x1FFFFu);
    }
    __syncthreads();

    // ---- (2) gather phase: 64 clusters x 16 lanes, fp8 rows, reg accum ----
    const int cl = t >> 4, ln = t & 15;
#pragma unroll
    for (int typ = 0; typ < 2; ++typ) {
        const int beg = ex[typ * 64 + cl];
        const int fin = beg + cnt[typ * 64 + cl];
        const ushort* lx = lidx[typ];
        float a[8] = {0.f,0.f,0.f,0.f,0.f,0.f,0.f,0.f};
#define ACC8(w) { \
    auto p0 = __builtin_amdgcn_cvt_pk_f32_fp8((int)(w).x, false); \
    auto p1 = __builtin_amdgcn_cvt_pk_f32_fp8((int)(w).x, true);  \
    auto p2 = __builtin_amdgcn_cvt_pk_f32_fp8((int)(w).y, false); \
    auto p3 = __builtin_amdgcn_cvt_pk_f32_fp8((int)(w).y, true);  \
    a[0]+=p0[0]; a[1]+=p0[1]; a[2]+=p1[0]; a[3]+=p1[1];           \
    a[4]+=p2[0]; a[5]+=p2[1]; a[6]+=p3[0]; a[7]+=p3[1]; }
        int e = beg;
        for (; e + 4 <= fin; e += 4) {
            uint2 w0 = feat8[(size_t)lx[e]     * 16 + ln];
            uint2 w1 = feat8[(size_t)lx[e + 1] * 16 + ln];
            uint2 w2 = feat8[(size_t)lx[e + 2] * 16 + ln];
            uint2 w3 = feat8[(size_t)lx[e + 3] * 16 + ln];
            ACC8(w0); ACC8(w1); ACC8(w2); ACC8(w3);
        }
        for (; e < fin; ++e) {
            uint2 w0 = feat8[(size_t)lx[e] * 16 + ln];
            ACC8(w0);
        }
#undef ACC8
        const float invd = 1.0f / fmaxf((float)(fin - beg), 1.0f);
        uint4 o;
        o.x = fp2bf_rn(a[0] * invd) | (fp2bf_rn(a[1] * invd) << 16);
        o.y = fp2bf_rn(a[2] * invd) | (fp2bf_rn(a[3] * invd) << 16);
        o.z = fp2bf_rn(a[4] * invd) | (fp2bf_rn(a[5] * invd) << 16);
        o.w = fp2bf_rn(a[6] * invd) | (fp2bf_rn(a[7] * invd) << 16);
        *reinterpret_cast<uint4*>(&mlds[(typ * BN + cl) * MPITCH + ln * 4]) = o;
    }
    __syncthreads();

    // ---- (3) GEMM phase: 64 rows x 128 cols, K = 12 x 32, 16 waves ----
    const int wid = t >> 6, wl = t & 63;
    const int mrow = wl & 15, g = wl >> 4;
    const int mt   = wid >> 2;             // 0..3
    const int ntp  = (wid & 3) * 2;        // 0,2,4,6
    const int arow = mt * 16 + mrow;       // 0..63

    f32x4 acc0 = (f32x4){0.f, 0.f, 0.f, 0.f};
    f32x4 acc1 = (f32x4){0.f, 0.f, 0.f, 0.f};
#pragma unroll
    for (int ks = 0; ks < 12; ++ks) {
        union { uint4 u; bf16x8 v; } av;
        if (ks < 8) {
            av.u = *reinterpret_cast<const uint4*>(
                &mlds[((ks >> 2) * BN + arow) * MPITCH + (ks & 3) * 16 + g * 4]);
        } else {
            int srow = b * BN + arow;
            if (srow >= N_NODES) srow = N_NODES - 1;
            av.u = feat[(size_t)srow * 16 + (ks & 3) * 4 + g];
        }
        const ushort* Wk = Wpack + (size_t)ks * 128 * 32;
        union { uint4 u; bf16x8 v; } bv0, bv1;
        bv0.u = *reinterpret_cast<const uint4*>(Wk + ((ntp * 16 + mrow) * 32 + g * 8));
        bv1.u = *reinterpret_cast<const uint4*>(Wk + (((ntp + 1) * 16 + mrow) * 32 + g * 8));
        acc0 = __builtin_amdgcn_mfma_f32_16x16x32_bf16(av.v, bv0.v, acc0, 0, 0, 0);
        acc1 = __builtin_amdgcn_mfma_f32_16x16x32_bf16(av.v, bv1.v, acc1, 0, 0, 0);
    }

    // ---- epilogue ----
#pragma unroll
    for (int q = 0; q < 2; ++q) {
        const f32x4 av = q ? acc1 : acc0;
        const int col = (ntp + q) * 16 + mrow;
        const float bias = bias0[col] + bias1[col];
#pragma unroll
        for (int r = 0; r < 4; ++r) {
            const int row = b * BN + mt * 16 + g * 4 + r;
            if (row < N_NODES) {
                const float v = av[r] + bias;
                if (act) {
                    outf[(size_t)row * D + col] = 1.0f / (1.0f + expf(-v));
                } else {
                    outb[(size_t)row * D + col] = (ushort)fp2bf_rn(v);
                    const int pk = __builtin_amdgcn_cvt_pk_fp8_f32(v, v, 0, false);
                    out8[(size_t)row * D + col] = (uchar)(pk & 0xFF);
                }
            }
        }
    }
}

// ---------------------------------------------------------------------------
extern "C" void kernel_launch(void* const* d_in, const int* in_sizes, int n_in,
                              void* d_out, int out_size, void* d_ws, size_t ws_size,
                              hipStream_t stream) {
    const float* x    = (const float*)d_in[0];
    const int*   ei_a = (const int*)d_in[2];
    const int*   ei_b = (const int*)d_in[3];
    const float* Wl   = (const float*)d_in[4];
    const float* bl   = (const float*)d_in[5];
    const float* Wr   = (const float*)d_in[6];
    float* out = (float*)d_out;

    // ---- workspace (~47 MB) ----
    ushort* featb = (ushort*)d_ws;                           // [N][128] bf16
    ushort* feat2 = featb + (size_t)N_NODES * D;             // [N][128] bf16
    uchar* feat8  = (uchar*)(feat2 + (size_t)N_NODES * D);   // [N][128] fp8
    uchar* feat28 = feat8 + (size_t)N_NODES * D;             // [N][128] fp8
    uint* ebufA = (uint*)(feat28 + (size_t)N_NODES * D);     // NBUCK*CAP
    uint* ebufB = ebufA + (size_t)NBUCK * CAP;
    int* bcurA  = (int*)(ebufB + (size_t)NBUCK * CAP);       // NBUCK
    int* bcurB  = bcurA + NBUCK;
    ushort* Wpack = (ushort*)(((size_t)(bcurB + NBUCK) + 63) & ~(size_t)63);

    const int* srcA = ei_a;
    const int* dstA = ei_a + NE;
    const int* srcB = ei_b;
    const int* dstB = ei_b + NE;

    hipMemsetAsync(bcurA, 0, 2ull * NBUCK * sizeof(int), stream);
    build_kernel<<<2 * PBLK + F2B_BLKS + WPREP_BLKS, 256, 0, stream>>>(
        (const float4*)x, (uint2*)featb, (uint*)feat8, Wl, Wr, Wpack,
        srcA, dstA, srcB, dstB, bcurA, bcurB, ebufA, ebufB);

    fused_kernel<<<NBUCK, 1024, 0, stream>>>(
        (const uint4*)featb, (const uint2*)feat8, ebufA, ebufB, bcurA, bcurB,
        Wpack, bl + 0 * D, bl + 1 * D, nullptr, feat2, feat28, 0);
    fused_kernel<<<NBUCK, 1024, 0, stream>>>(
        (const uint4*)feat2, (const uint2*)feat28, ebufA, ebufB, bcurA, bcurB,
        Wpack + (size_t)12 * 128 * 32, bl + 2 * D, bl + 3 * D, out, nullptr, nullptr, 1);
}

// Round 13
// 171.540 us; speedup vs baseline: 1.1973x; 1.0363x over previous
//
#include <hip/hip_runtime.h>
#include <math.h>

#define N_NODES 50000
#define D 128
#define NE 800000
#define BN 64                  // nodes per bucket (dst >> 6)
#define NBUCK 782              // ceil(N_NODES / 64)
#define CAP 1280               // records per bucket (mean 1024, 8 sigma)
#define EPB 4096               // edges per partition block
#define PBLK 196               // ceil(NE / EPB)
#define F2B_BLKS 6250          // N*D/4 / 256
#define WPREP_BLKS 384         // 2*12*128*32 / 256
#define MPITCH 68              // uint pitch for LDS mean rows

typedef unsigned int uint;
typedef unsigned short ushort;
typedef unsigned char uchar;

using bf16x8 = __attribute__((ext_vector_type(8))) short;
using f32x4  = __attribute__((ext_vector_type(4))) float;

// ---- bf16 helpers (bit-level, RN-even) ----
__device__ __forceinline__ float bflo(uint w) {
    union { uint u; float f; } c; c.u = w << 16; return c.f;
}
__device__ __forceinline__ float bfhi(uint w) {
    union { uint u; float f; } c; c.u = w & 0xffff0000u; return c.f;
}
__device__ __forceinline__ uint fp2bf_rn(float f) {
    union { float f; uint u; } c; c.f = f;
    return (c.u + 0x7fffu + ((c.u >> 16) & 1u)) >> 16;
}

// ---------------------------------------------------------------------------
// build: [0, 2*PBLK) edge partition into 64-node bucket record runs;
//        then x -> bf16 + fp8; then W pre-pack.
// rec = src | (dst&63)<<17.  After this kernel bcur[b] = bucket record count.
// ---------------------------------------------------------------------------
__global__ __launch_bounds__(256) void build_kernel(
    const float4* __restrict__ x4, uint2* __restrict__ featb2,
    uint* __restrict__ feat8w,
    const float* __restrict__ Wl, const float* __restrict__ Wr,
    ushort* __restrict__ Wpack,
    const int* __restrict__ srcA, const int* __restrict__ dstA,
    const int* __restrict__ srcB, const int* __restrict__ dstB,
    int* __restrict__ bcurA, int* __restrict__ bcurB,
    uint* __restrict__ ebufA, uint* __restrict__ ebufB) {
    const int blk = blockIdx.x;
    const int t   = threadIdx.x;
    if (blk < 2 * PBLK) {
        __shared__ int h[NBUCK];
        __shared__ int base[NBUCK];
        const int typ = blk >= PBLK;
        const int* src = typ ? srcB : srcA;
        const int* dst = typ ? dstB : dstA;
        int* bc        = typ ? bcurB : bcurA;
        uint* ebuf     = typ ? ebufB : ebufA;
        const int e0 = (blk - (typ ? PBLK : 0)) * EPB;
        for (int j = t; j < NBUCK; j += 256) h[j] = 0;
        __syncthreads();
#pragma unroll
        for (int i = 0; i < EPB / 256; ++i) {
            const int e = e0 + t + i * 256;
            if (e < NE) atomicAdd(&h[dst[e] >> 6], 1);
        }
        __syncthreads();
        for (int j = t; j < NBUCK; j += 256) {
            const int c = h[j];
            base[j] = c ? atomicAdd(&bc[j], c) : 0;
            h[j] = 0;                    // reuse as local cursor
        }
        __syncthreads();
#pragma unroll
        for (int i = 0; i < EPB / 256; ++i) {
            const int e = e0 + t + i * 256;
            if (e < NE) {
                const int d  = dst[e];
                const int bk = d >> 6;
                const int pos = atomicAdd(&h[bk], 1);
                const int off = base[bk] + pos;
                if (off < CAP)
                    ebuf[(size_t)bk * CAP + off] = (uint)src[e] | ((uint)(d & 63) << 17);
            }
        }
    } else if (blk < 2 * PBLK + F2B_BLKS) {
        const int i = (blk - 2 * PBLK) * 256 + t;
        float4 v = x4[i];
        uint2 o;
        o.x = fp2bf_rn(v.x) | (fp2bf_rn(v.y) << 16);
        o.y = fp2bf_rn(v.z) | (fp2bf_rn(v.w) << 16);
        featb2[i] = o;
        int pk = __builtin_amdgcn_cvt_pk_fp8_f32(v.x, v.y, 0, false);
        pk = __builtin_amdgcn_cvt_pk_fp8_f32(v.z, v.w, pk, true);
        feat8w[i] = (uint)pk;
    } else {
        const int i   = (blk - 2 * PBLK - F2B_BLKS) * 256 + t;  // [2][12][128][32]
        const int l   = i / 49152;
        const int rem = i % 49152;
        const int ks  = rem / 4096;
        const int n   = (rem % 4096) / 32;
        const int kk  = rem % 32;
        const int r   = ks * 32 + kk;
        float v;
        if (r < 128)       v = Wl[(((size_t)l * 2 + 0) * 128 + r) * 128 + n];
        else if (r < 256)  v = Wl[(((size_t)l * 2 + 1) * 128 + (r - 128)) * 128 + n];
        else               v = Wr[(((size_t)l * 2 + 0) * 128 + (r - 256)) * 128 + n]
                             + Wr[(((size_t)l * 2 + 1) * 128 + (r - 256)) * 128 + n];
        Wpack[i] = (ushort)fp2bf_rn(v);
    }
}

// ---------------------------------------------------------------------------
// fused: one block per 64-node bucket:
//  (1) stage bucket records in LDS; per-node count/scan/place (in-LDS sort)
//  (1b) counting-rank the 128 lists by length (LPT balance)
//  (2) gather means from FP8 features; cluster cl takes A-rank[cl] and
//      B-rank[63-cl] (balanced totals, no wave divergence); unroll-8;
//      register accumulation -> bf16 means in LDS
//  (3) 64x128 MFMA GEMM over K=384 = [meanA|meanB|self] (bf16)
//      out[i,:] = act( meanA@W0 + meanB@W1 + self@(Wr0+Wr1) + b0+b1 )
// 1024 threads = 16 waves; 64 gather clusters x 16 lanes.
// ---------------------------------------------------------------------------
__global__ __launch_bounds__(1024, 8) void fused_kernel(
    const uint4* __restrict__ feat,      // layer input bf16 [N][16] (self/GEMM)
    const uint2* __restrict__ feat8,     // layer input fp8 [N][16] (gather)
    const uint* __restrict__ ebufA, const uint* __restrict__ ebufB,
    const int* __restrict__ bcntA, const int* __restrict__ bcntB,
    const ushort* __restrict__ Wpack,    // [12][128][32] bf16 for this layer
    const float* __restrict__ bias0, const float* __restrict__ bias1,
    float* __restrict__ outf, ushort* __restrict__ outb,
    uchar* __restrict__ out8, int act) {

    __shared__ uint   mlds[2 * BN * MPITCH];   // bf16 means  (34816 B)
    __shared__ uint   rlds[2][CAP];            // staged records (10240 B)
    __shared__ ushort lidx[2][CAP];            // per-node src lists (5120 B)
    __shared__ int    cnt[128], ex[128], cur[128];
    __shared__ uchar  rankedA[64], rankedB[64];

    const int b = blockIdx.x;
    const int t = threadIdx.x;

    // ---- (1) stage records + per-node sort ----
    if (t < 128) cnt[t] = 0;
    int countA = bcntA[b]; if (countA > CAP) countA = CAP;
    int countB = bcntB[b]; if (countB > CAP) countB = CAP;
    const uint* ebA = ebufA + (size_t)b * CAP;
    const uint* ebB = ebufB + (size_t)b * CAP;
    for (int e = t; e < countA; e += 1024) rlds[0][e] = ebA[e];
    for (int e = t; e < countB; e += 1024) rlds[1][e] = ebB[e];
    __syncthreads();
    for (int e = t; e < countA; e += 1024) atomicAdd(&cnt[rlds[0][e] >> 17], 1);
    for (int e = t; e < countB; e += 1024) atomicAdd(&cnt[64 + (rlds[1][e] >> 17)], 1);
    __syncthreads();
    if (t < 128) ex[t] = cnt[t];
    __syncthreads();
    // two independent 64-wide Hillis-Steele scans (threads 0-63 and 64-127)
    for (int off = 1; off < 64; off <<= 1) {
        int v = 0;
        if (t < 128 && (t & 63) >= off) v = ex[t - off];
        __syncthreads();
        if (t < 128 && (t & 63) >= off) ex[t] += v;
        __syncthreads();
    }
    if (t < 128) { ex[t] -= cnt[t]; cur[t] = ex[t]; }   // exclusive base
    __syncthreads();
    for (int e = t; e < countA; e += 1024) {
        const uint rec = rlds[0][e];
        const int p = atomicAdd(&cur[rec >> 17], 1);
        lidx[0][p] = (ushort)(rec & 0x1FFFFu);
    }
    for (int e = t; e < countB; e += 1024) {
        const uint rec = rlds[1][e];
        const int p = atomicAdd(&cur[64 + (rec >> 17)], 1);
        lidx[1][p] = (ushort)(rec & 0x1FFFFu);
    }
    // ---- (1b) counting rank by list length (desc), per type ----
    if (t < 128) {
        const int typ = t >> 6, i = t & 63;
        const int li = cnt[t];
        const int base = typ * 64;
        int r = 0;
#pragma unroll 8
        for (int j = 0; j < 64; ++j) {
            const int lj = cnt[base + j];
            r += (lj > li) || (lj == li && j < i);
        }
        if (typ == 0) rankedA[r] = (uchar)i; else rankedB[r] = (uchar)i;
    }
    __syncthreads();

    // ---- (2) gather phase: balanced cluster->list mapping, fp8 rows ----
    const int cl = t >> 4, ln = t & 15;
#pragma unroll
    for (int typ = 0; typ < 2; ++typ) {
        const int node = typ ? (int)rankedB[63 - cl] : (int)rankedA[cl];
        const int slot = typ * 64 + node;
        const int beg = ex[slot];
        const int deg = cnt[slot];
        const int fin = beg + deg;
        const ushort* lx = lidx[typ];
        float a[8] = {0.f,0.f,0.f,0.f,0.f,0.f,0.f,0.f};
#define ACC8(w) { \
    auto p0 = __builtin_amdgcn_cvt_pk_f32_fp8((int)(w).x, false); \
    auto p1 = __builtin_amdgcn_cvt_pk_f32_fp8((int)(w).x, true);  \
    auto p2 = __builtin_amdgcn_cvt_pk_f32_fp8((int)(w).y, false); \
    auto p3 = __builtin_amdgcn_cvt_pk_f32_fp8((int)(w).y, true);  \
    a[0]+=p0[0]; a[1]+=p0[1]; a[2]+=p1[0]; a[3]+=p1[1];           \
    a[4]+=p2[0]; a[5]+=p2[1]; a[6]+=p3[0]; a[7]+=p3[1]; }
        int e = beg;
        for (; e + 8 <= fin; e += 8) {
            uint2 w0 = feat8[(size_t)lx[e]     * 16 + ln];
            uint2 w1 = feat8[(size_t)lx[e + 1] * 16 + ln];
            uint2 w2 = feat8[(size_t)lx[e + 2] * 16 + ln];
            uint2 w3 = feat8[(size_t)lx[e + 3] * 16 + ln];
            uint2 w4 = feat8[(size_t)lx[e + 4] * 16 + ln];
            uint2 w5 = feat8[(size_t)lx[e + 5] * 16 + ln];
            uint2 w6 = feat8[(size_t)lx[e + 6] * 16 + ln];
            uint2 w7 = feat8[(size_t)lx[e + 7] * 16 + ln];
            ACC8(w0); ACC8(w1); ACC8(w2); ACC8(w3);
            ACC8(w4); ACC8(w5); ACC8(w6); ACC8(w7);
        }
        if (e + 4 <= fin) {
            uint2 w0 = feat8[(size_t)lx[e]     * 16 + ln];
            uint2 w1 = feat8[(size_t)lx[e + 1] * 16 + ln];
            uint2 w2 = feat8[(size_t)lx[e + 2] * 16 + ln];
            uint2 w3 = feat8[(size_t)lx[e + 3] * 16 + ln];
            ACC8(w0); ACC8(w1); ACC8(w2); ACC8(w3);
            e += 4;
        }
        for (; e < fin; ++e) {
            uint2 w0 = feat8[(size_t)lx[e] * 16 + ln];
            ACC8(w0);
        }
#undef ACC8
        const float invd = 1.0f / fmaxf((float)deg, 1.0f);
        uint4 o;
        o.x = fp2bf_rn(a[0] * invd) | (fp2bf_rn(a[1] * invd) << 16);
        o.y = fp2bf_rn(a[2] * invd) | (fp2bf_rn(a[3] * invd) << 16);
        o.z = fp2bf_rn(a[4] * invd) | (fp2bf_rn(a[5] * invd) << 16);
        o.w = fp2bf_rn(a[6] * invd) | (fp2bf_rn(a[7] * invd) << 16);
        *reinterpret_cast<uint4*>(&mlds[(typ * BN + node) * MPITCH + ln * 4]) = o;
    }
    __syncthreads();

    // ---- (3) GEMM phase: 64 rows x 128 cols, K = 12 x 32, 16 waves ----
    const int wid = t >> 6, wl = t & 63;
    const int mrow = wl & 15, g = wl >> 4;
    const int mt   = wid >> 2;             // 0..3
    const int ntp  = (wid & 3) * 2;        // 0,2,4,6
    const int arow = mt * 16 + mrow;       // 0..63

    f32x4 acc0 = (f32x4){0.f, 0.f, 0.f, 0.f};
    f32x4 acc1 = (f32x4){0.f, 0.f, 0.f, 0.f};
#pragma unroll
    for (int ks = 0; ks < 12; ++ks) {
        union { uint4 u; bf16x8 v; } av;
        if (ks < 8) {
            av.u = *reinterpret_cast<const uint4*>(
                &mlds[((ks >> 2) * BN + arow) * MPITCH + (ks & 3) * 16 + g * 4]);
        } else {
            int srow = b * BN + arow;
            if (srow >= N_NODES) srow = N_NODES - 1;
            av.u = feat[(size_t)srow * 16 + (ks & 3) * 4 + g];
        }
        const ushort* Wk = Wpack + (size_t)ks * 128 * 32;
        union { uint4 u; bf16x8 v; } bv0, bv1;
        bv0.u = *reinterpret_cast<const uint4*>(Wk + ((ntp * 16 + mrow) * 32 + g * 8));
        bv1.u = *reinterpret_cast<const uint4*>(Wk + (((ntp + 1) * 16 + mrow) * 32 + g * 8));
        acc0 = __builtin_amdgcn_mfma_f32_16x16x32_bf16(av.v, bv0.v, acc0, 0, 0, 0);
        acc1 = __builtin_amdgcn_mfma_f32_16x16x32_bf16(av.v, bv1.v, acc1, 0, 0, 0);
    }

    // ---- epilogue ----
#pragma unroll
    for (int q = 0; q < 2; ++q) {
        const f32x4 av = q ? acc1 : acc0;
        const int col = (ntp + q) * 16 + mrow;
        const float bias = bias0[col] + bias1[col];
#pragma unroll
        for (int r = 0; r < 4; ++r) {
            const int row = b * BN + mt * 16 + g * 4 + r;
            if (row < N_NODES) {
                const float v = av[r] + bias;
                if (act) {
                    outf[(size_t)row * D + col] = 1.0f / (1.0f + expf(-v));
                } else {
                    outb[(size_t)row * D + col] = (ushort)fp2bf_rn(v);
                    const int pk = __builtin_amdgcn_cvt_pk_fp8_f32(v, v, 0, false);
                    out8[(size_t)row * D + col] = (uchar)(pk & 0xFF);
                }
            }
        }
    }
}

// ---------------------------------------------------------------------------
extern "C" void kernel_launch(void* const* d_in, const int* in_sizes, int n_in,
                              void* d_out, int out_size, void* d_ws, size_t ws_size,
                              hipStream_t stream) {
    const float* x    = (const float*)d_in[0];
    const int*   ei_a = (const int*)d_in[2];
    const int*   ei_b = (const int*)d_in[3];
    const float* Wl   = (const float*)d_in[4];
    const float* bl   = (const float*)d_in[5];
    const float* Wr   = (const float*)d_in[6];
    float* out = (float*)d_out;

    // ---- workspace (~47 MB) ----
    ushort* featb = (ushort*)d_ws;                           // [N][128] bf16
    ushort* feat2 = featb + (size_t)N_NODES * D;             // [N][128] bf16
    uchar* feat8  = (uchar*)(feat2 + (size_t)N_NODES * D);   // [N][128] fp8
    uchar* feat28 = feat8 + (size_t)N_NODES * D;             // [N][128] fp8
    uint* ebufA = (uint*)(feat28 + (size_t)N_NODES * D);     // NBUCK*CAP
    uint* ebufB = ebufA + (size_t)NBUCK * CAP;
    int* bcurA  = (int*)(ebufB + (size_t)NBUCK * CAP);       // NBUCK
    int* bcurB  = bcurA + NBUCK;
    ushort* Wpack = (ushort*)(((size_t)(bcurB + NBUCK) + 63) & ~(size_t)63);

    const int* srcA = ei_a;
    const int* dstA = ei_a + NE;
    const int* srcB = ei_b;
    const int* dstB = ei_b + NE;

    hipMemsetAsync(bcurA, 0, 2ull * NBUCK * sizeof(int), stream);
    build_kernel<<<2 * PBLK + F2B_BLKS + WPREP_BLKS, 256, 0, stream>>>(
        (const float4*)x, (uint2*)featb, (uint*)feat8, Wl, Wr, Wpack,
        srcA, dstA, srcB, dstB, bcurA, bcurB, ebufA, ebufB);

    fused_kernel<<<NBUCK, 1024, 0, stream>>>(
        (const uint4*)featb, (const uint2*)feat8, ebufA, ebufB, bcurA, bcurB,
        Wpack, bl + 0 * D, bl + 1 * D, nullptr, feat2, feat28, 0);
    fused_kernel<<<NBUCK, 1024, 0, stream>>>(
        (const uint4*)feat2, (const uint2*)feat28, ebufA, ebufB, bcurA, bcurB,
        Wpack + (size_t)12 * 128 * 32, bl + 2 * D, bl + 3 * D, out, nullptr, nullptr, 1);
}

// Round 14
// 171.055 us; speedup vs baseline: 1.2007x; 1.0028x over previous
//
#include <hip/hip_runtime.h>
#include <math.h>

#define N_NODES 50000
#define D 128
#define NE 800000
#define BN 64                  // nodes per bucket (dst >> 6)
#define NBUCK 782              // ceil(N_NODES / 64)
#define CAP 1280               // records per bucket (mean 1024, 8 sigma)
#define EPB 4096               // edges per partition block
#define PBLK 196               // ceil(NE / EPB)
#define F2B_BLKS 6250          // N*D/4 / 256
#define WPREP_BLKS 384         // 2*12*128*32 / 256
#define MPITCH 68              // uint pitch for LDS mean rows

typedef unsigned int uint;
typedef unsigned short ushort;
typedef unsigned char uchar;

using bf16x8 = __attribute__((ext_vector_type(8))) short;
using f32x4  = __attribute__((ext_vector_type(4))) float;

// ---- bf16 helpers (bit-level, RN-even) ----
__device__ __forceinline__ float bflo(uint w) {
    union { uint u; float f; } c; c.u = w << 16; return c.f;
}
__device__ __forceinline__ float bfhi(uint w) {
    union { uint u; float f; } c; c.u = w & 0xffff0000u; return c.f;
}
__device__ __forceinline__ uint fp2bf_rn(float f) {
    union { float f; uint u; } c; c.f = f;
    return (c.u + 0x7fffu + ((c.u >> 16) & 1u)) >> 16;
}

// ---------------------------------------------------------------------------
// build: [0, 2*PBLK) edge partition into 64-node bucket record runs;
//        then x -> bf16 + fp8; then W pre-pack.
// rec = src | (dst&63)<<17.  After this kernel bcur[b] = bucket record count.
// ---------------------------------------------------------------------------
__global__ __launch_bounds__(256) void build_kernel(
    const float4* __restrict__ x4, uint2* __restrict__ featb2,
    uint* __restrict__ feat8w,
    const float* __restrict__ Wl, const float* __restrict__ Wr,
    ushort* __restrict__ Wpack,
    const int* __restrict__ srcA, const int* __restrict__ dstA,
    const int* __restrict__ srcB, const int* __restrict__ dstB,
    int* __restrict__ bcurA, int* __restrict__ bcurB,
    uint* __restrict__ ebufA, uint* __restrict__ ebufB) {
    const int blk = blockIdx.x;
    const int t   = threadIdx.x;
    if (blk < 2 * PBLK) {
        __shared__ int h[NBUCK];
        __shared__ int base[NBUCK];
        const int typ = blk >= PBLK;
        const int* src = typ ? srcB : srcA;
        const int* dst = typ ? dstB : dstA;
        int* bc        = typ ? bcurB : bcurA;
        uint* ebuf     = typ ? ebufB : ebufA;
        const int e0 = (blk - (typ ? PBLK : 0)) * EPB;
        for (int j = t; j < NBUCK; j += 256) h[j] = 0;
        __syncthreads();
#pragma unroll
        for (int i = 0; i < EPB / 256; ++i) {
            const int e = e0 + t + i * 256;
            if (e < NE) atomicAdd(&h[dst[e] >> 6], 1);
        }
        __syncthreads();
        for (int j = t; j < NBUCK; j += 256) {
            const int c = h[j];
            base[j] = c ? atomicAdd(&bc[j], c) : 0;
            h[j] = 0;                    // reuse as local cursor
        }
        __syncthreads();
#pragma unroll
        for (int i = 0; i < EPB / 256; ++i) {
            const int e = e0 + t + i * 256;
            if (e < NE) {
                const int d  = dst[e];
                const int bk = d >> 6;
                const int pos = atomicAdd(&h[bk], 1);
                const int off = base[bk] + pos;
                if (off < CAP)
                    ebuf[(size_t)bk * CAP + off] = (uint)src[e] | ((uint)(d & 63) << 17);
            }
        }
    } else if (blk < 2 * PBLK + F2B_BLKS) {
        const int i = (blk - 2 * PBLK) * 256 + t;
        float4 v = x4[i];
        uint2 o;
        o.x = fp2bf_rn(v.x) | (fp2bf_rn(v.y) << 16);
        o.y = fp2bf_rn(v.z) | (fp2bf_rn(v.w) << 16);
        featb2[i] = o;
        int pk = __builtin_amdgcn_cvt_pk_fp8_f32(v.x, v.y, 0, false);
        pk = __builtin_amdgcn_cvt_pk_fp8_f32(v.z, v.w, pk, true);
        feat8w[i] = (uint)pk;
    } else {
        const int i   = (blk - 2 * PBLK - F2B_BLKS) * 256 + t;  // [2][12][128][32]
        const int l   = i / 49152;
        const int rem = i % 49152;
        const int ks  = rem / 4096;
        const int n   = (rem % 4096) / 32;
        const int kk  = rem % 32;
        const int r   = ks * 32 + kk;
        float v;
        if (r < 128)       v = Wl[(((size_t)l * 2 + 0) * 128 + r) * 128 + n];
        else if (r < 256)  v = Wl[(((size_t)l * 2 + 1) * 128 + (r - 128)) * 128 + n];
        else               v = Wr[(((size_t)l * 2 + 0) * 128 + (r - 256)) * 128 + n]
                             + Wr[(((size_t)l * 2 + 1) * 128 + (r - 256)) * 128 + n];
        Wpack[i] = (ushort)fp2bf_rn(v);
    }
}

// ---------------------------------------------------------------------------
// fused: one block per 64-node bucket:
//  (1) stage bucket records in LDS; per-node count/scan/place (in-LDS sort)
//  (1b) counting-rank the 128 lists by length (LPT balance)
//  (2) gather means from FP8 features; cluster cl takes A-rank[cl] and
//      B-rank[63-cl] (balanced totals, no wave divergence); unroll-8;
//      register accumulation -> bf16 means in LDS
//  (3) 64x128 MFMA GEMM over K=384 = [meanA|meanB|self] (bf16)
//      out[i,:] = act( meanA@W0 + meanB@W1 + self@(Wr0+Wr1) + b0+b1 )
// 1024 threads = 16 waves; 64 gather clusters x 16 lanes.
// ---------------------------------------------------------------------------
__global__ __launch_bounds__(1024, 8) void fused_kernel(
    const uint4* __restrict__ feat,      // layer input bf16 [N][16] (self/GEMM)
    const uint2* __restrict__ feat8,     // layer input fp8 [N][16] (gather)
    const uint* __restrict__ ebufA, const uint* __restrict__ ebufB,
    const int* __restrict__ bcntA, const int* __restrict__ bcntB,
    const ushort* __restrict__ Wpack,    // [12][128][32] bf16 for this layer
    const float* __restrict__ bias0, const float* __restrict__ bias1,
    float* __restrict__ outf, ushort* __restrict__ outb,
    uchar* __restrict__ out8, int act) {

    __shared__ uint   mlds[2 * BN * MPITCH];   // bf16 means  (34816 B)
    __shared__ uint   rlds[2][CAP];            // staged records (10240 B)
    __shared__ ushort lidx[2][CAP];            // per-node src lists (5120 B)
    __shared__ int    cnt[128], ex[128], cur[128];
    __shared__ uchar  rankedA[64], rankedB[64];

    const int b = blockIdx.x;
    const int t = threadIdx.x;

    // ---- (1) stage records + per-node sort ----
    if (t < 128) cnt[t] = 0;
    int countA = bcntA[b]; if (countA > CAP) countA = CAP;
    int countB = bcntB[b]; if (countB > CAP) countB = CAP;
    const uint* ebA = ebufA + (size_t)b * CAP;
    const uint* ebB = ebufB + (size_t)b * CAP;
    for (int e = t; e < countA; e += 1024) rlds[0][e] = ebA[e];
    for (int e = t; e < countB; e += 1024) rlds[1][e] = ebB[e];
    __syncthreads();
    for (int e = t; e < countA; e += 1024) atomicAdd(&cnt[rlds[0][e] >> 17], 1);
    for (int e = t; e < countB; e += 1024) atomicAdd(&cnt[64 + (rlds[1][e] >> 17)], 1);
    __syncthreads();
    if (t < 128) ex[t] = cnt[t];
    __syncthreads();
    // two independent 64-wide Hillis-Steele scans (threads 0-63 and 64-127)
    for (int off = 1; off < 64; off <<= 1) {
        int v = 0;
        if (t < 128 && (t & 63) >= off) v = ex[t - off];
        __syncthreads();
        if (t < 128 && (t & 63) >= off) ex[t] += v;
        __syncthreads();
    }
    if (t < 128) { ex[t] -= cnt[t]; cur[t] = ex[t]; }   // exclusive base
    __syncthreads();
    for (int e = t; e < countA; e += 1024) {
        const uint rec = rlds[0][e];
        const int p = atomicAdd(&cur[rec >> 17], 1);
        lidx[0][p] = (ushort)(rec & 0x1FFFFu);
    }
    for (int e = t; e < countB; e += 1024) {
        const uint rec = rlds[1][e];
        const int p = atomicAdd(&cur[64 + (rec >> 17)], 1);
        lidx[1][p] = (ushort)(rec & 0x1FFFFu);
    }
    // ---- (1b) counting rank by list length (desc), per type ----
    if (t < 128) {
        const int typ = t >> 6, i = t & 63;
        const int li = cnt[t];
        const int base = typ * 64;
        int r = 0;
#pragma unroll 8
        for (int j = 0; j < 64; ++j) {
            const int lj = cnt[base + j];
            r += (lj > li) || (lj == li && j < i);
        }
        if (typ == 0) rankedA[r] = (uchar)i; else rankedB[r] = (uchar)i;
    }
    __syncthreads();

    // ---- (2) gather phase: balanced cluster->list mapping, fp8 rows ----
    const int cl = t >> 4, ln = t & 15;
#pragma unroll
    for (int typ = 0; typ < 2; ++typ) {
        const int node = typ ? (int)rankedB[63 - cl] : (int)rankedA[cl];
        const int slot = typ * 64 + node;
        const int beg = ex[slot];
        const int deg = cnt[slot];
        const int fin = beg + deg;
        const ushort* lx = lidx[typ];
        float a[8] = {0.f,0.f,0.f,0.f,0.f,0.f,0.f,0.f};
#define ACC8(w) { \
    auto p0 = __builtin_amdgcn_cvt_pk_f32_fp8((int)(w).x, false); \
    auto p1 = __builtin_amdgcn_cvt_pk_f32_fp8((int)(w).x, true);  \
    auto p2 = __builtin_amdgcn_cvt_pk_f32_fp8((int)(w).y, false); \
    auto p3 = __builtin_amdgcn_cvt_pk_f32_fp8((int)(w).y, true);  \
    a[0]+=p0[0]; a[1]+=p0[1]; a[2]+=p1[0]; a[3]+=p1[1];           \
    a[4]+=p2[0]; a[5]+=p2[1]; a[6]+=p3[0]; a[7]+=p3[1]; }
        int e = beg;
        for (; e + 8 <= fin; e += 8) {
            uint2 w0 = feat8[(size_t)lx[e]     * 16 + ln];
            uint2 w1 = feat8[(size_t)lx[e + 1] * 16 + ln];
            uint2 w2 = feat8[(size_t)lx[e + 2] * 16 + ln];
            uint2 w3 = feat8[(size_t)lx[e + 3] * 16 + ln];
            uint2 w4 = feat8[(size_t)lx[e + 4] * 16 + ln];
            uint2 w5 = feat8[(size_t)lx[e + 5] * 16 + ln];
            uint2 w6 = feat8[(size_t)lx[e + 6] * 16 + ln];
            uint2 w7 = feat8[(size_t)lx[e + 7] * 16 + ln];
            ACC8(w0); ACC8(w1); ACC8(w2); ACC8(w3);
            ACC8(w4); ACC8(w5); ACC8(w6); ACC8(w7);
        }
        if (e + 4 <= fin) {
            uint2 w0 = feat8[(size_t)lx[e]     * 16 + ln];
            uint2 w1 = feat8[(size_t)lx[e + 1] * 16 + ln];
            uint2 w2 = feat8[(size_t)lx[e + 2] * 16 + ln];
            uint2 w3 = feat8[(size_t)lx[e + 3] * 16 + ln];
            ACC8(w0); ACC8(w1); ACC8(w2); ACC8(w3);
            e += 4;
        }
        for (; e < fin; ++e) {
            uint2 w0 = feat8[(size_t)lx[e] * 16 + ln];
            ACC8(w0);
        }
#undef ACC8
        const float invd = 1.0f / fmaxf((float)deg, 1.0f);
        uint4 o;
        o.x = fp2bf_rn(a[0] * invd) | (fp2bf_rn(a[1] * invd) << 16);
        o.y = fp2bf_rn(a[2] * invd) | (fp2bf_rn(a[3] * invd) << 16);
        o.z = fp2bf_rn(a[4] * invd) | (fp2bf_rn(a[5] * invd) << 16);
        o.w = fp2bf_rn(a[6] * invd) | (fp2bf_rn(a[7] * invd) << 16);
        *reinterpret_cast<uint4*>(&mlds[(typ * BN + node) * MPITCH + ln * 4]) = o;
    }
    __syncthreads();

    // ---- (3) GEMM phase: 64 rows x 128 cols, K = 12 x 32, 16 waves ----
    const int wid = t >> 6, wl = t & 63;
    const int mrow = wl & 15, g = wl >> 4;
    const int mt   = wid >> 2;             // 0..3
    const int ntp  = (wid & 3) * 2;        // 0,2,4,6
    const int arow = mt * 16 + mrow;       // 0..63

    f32x4 acc0 = (f32x4){0.f, 0.f, 0.f, 0.f};
    f32x4 acc1 = (f32x4){0.f, 0.f, 0.f, 0.f};
#pragma unroll
    for (int ks = 0; ks < 12; ++ks) {
        union { uint4 u; bf16x8 v; } av;
        if (ks < 8) {
            av.u = *reinterpret_cast<const uint4*>(
                &mlds[((ks >> 2) * BN + arow) * MPITCH + (ks & 3) * 16 + g * 4]);
        } else {
            int srow = b * BN + arow;
            if (srow >= N_NODES) srow = N_NODES - 1;
            av.u = feat[(size_t)srow * 16 + (ks & 3) * 4 + g];
        }
        const ushort* Wk = Wpack + (size_t)ks * 128 * 32;
        union { uint4 u; bf16x8 v; } bv0, bv1;
        bv0.u = *reinterpret_cast<const uint4*>(Wk + ((ntp * 16 + mrow) * 32 + g * 8));
        bv1.u = *reinterpret_cast<const uint4*>(Wk + (((ntp + 1) * 16 + mrow) * 32 + g * 8));
        acc0 = __builtin_amdgcn_mfma_f32_16x16x32_bf16(av.v, bv0.v, acc0, 0, 0, 0);
        acc1 = __builtin_amdgcn_mfma_f32_16x16x32_bf16(av.v, bv1.v, acc1, 0, 0, 0);
    }

    // ---- epilogue ----
#pragma unroll
    for (int q = 0; q < 2; ++q) {
        const f32x4 av = q ? acc1 : acc0;
        const int col = (ntp + q) * 16 + mrow;
        const float bias = bias0[col] + bias1[col];
#pragma unroll
        for (int r = 0; r < 4; ++r) {
            const int row = b * BN + mt * 16 + g * 4 + r;
            if (row < N_NODES) {
                const float v = av[r] + bias;
                if (act) {
                    outf[(size_t)row * D + col] = 1.0f / (1.0f + expf(-v));
                } else {
                    outb[(size_t)row * D + col] = (ushort)fp2bf_rn(v);
                    const int pk = __builtin_amdgcn_cvt_pk_fp8_f32(v, v, 0, false);
                    out8[(size_t)row * D + col] = (uchar)(pk & 0xFF);
                }
            }
        }
    }
}

// ---------------------------------------------------------------------------
extern "C" void kernel_launch(void* const* d_in, const int* in_sizes, int n_in,
                              void* d_out, int out_size, void* d_ws, size_t ws_size,
                              hipStream_t stream) {
    const float* x    = (const float*)d_in[0];
    const int*   ei_a = (const int*)d_in[2];
    const int*   ei_b = (const int*)d_in[3];
    const float* Wl   = (const float*)d_in[4];
    const float* bl   = (const float*)d_in[5];
    const float* Wr   = (const float*)d_in[6];
    float* out = (float*)d_out;

    // ---- workspace (~47 MB) ----
    ushort* featb = (ushort*)d_ws;                           // [N][128] bf16
    ushort* feat2 = featb + (size_t)N_NODES * D;             // [N][128] bf16
    uchar* feat8  = (uchar*)(feat2 + (size_t)N_NODES * D);   // [N][128] fp8
    uchar* feat28 = feat8 + (size_t)N_NODES * D;             // [N][128] fp8
    uint* ebufA = (uint*)(feat28 + (size_t)N_NODES * D);     // NBUCK*CAP
    uint* ebufB = ebufA + (size_t)NBUCK * CAP;
    int* bcurA  = (int*)(ebufB + (size_t)NBUCK * CAP);       // NBUCK
    int* bcurB  = bcurA + NBUCK;
    ushort* Wpack = (ushort*)(((size_t)(bcurB + NBUCK) + 63) & ~(size_t)63);

    const int* srcA = ei_a;
    const int* dstA = ei_a + NE;
    const int* srcB = ei_b;
    const int* dstB = ei_b + NE;

    hipMemsetAsync(bcurA, 0, 2ull * NBUCK * sizeof(int), stream);
    build_kernel<<<2 * PBLK + F2B_BLKS + WPREP_BLKS, 256, 0, stream>>>(
        (const float4*)x, (uint2*)featb, (uint*)feat8, Wl, Wr, Wpack,
        srcA, dstA, srcB, dstB, bcurA, bcurB, ebufA, ebufB);

    fused_kernel<<<NBUCK, 1024, 0, stream>>>(
        (const uint4*)featb, (const uint2*)feat8, ebufA, ebufB, bcurA, bcurB,
        Wpack, bl + 0 * D, bl + 1 * D, nullptr, feat2, feat28, 0);
    fused_kernel<<<NBUCK, 1024, 0, stream>>>(
        (const uint4*)feat2, (const uint2*)feat28, ebufA, ebufB, bcurA, bcurB,
        Wpack + (size_t)12 * 128 * 32, bl + 2 * D, bl + 3 * D, out, nullptr, nullptr, 1);
}

// Round 15
// 170.693 us; speedup vs baseline: 1.2033x; 1.0021x over previous
//
#include <hip/hip_runtime.h>
#include <math.h>

#define N_NODES 50000
#define D 128
#define NE 800000
#define BN 64                  // nodes per bucket (dst >> 6)
#define NBUCK 782              // ceil(N_NODES / 64)
#define CAP 1280               // records per bucket (mean 1024, 8 sigma)
#define EPB 4096               // edges per partition block
#define PBLK 196               // ceil(NE / EPB)
#define F2B_BLKS 6250          // N*D/4 / 256
#define WPREP_BLKS 384         // 2*12*128*32 / 256
#define MPITCH 68              // uint pitch for LDS mean rows

typedef unsigned int uint;
typedef unsigned short ushort;
typedef unsigned char uchar;

using bf16x8 = __attribute__((ext_vector_type(8))) short;
using f32x4  = __attribute__((ext_vector_type(4))) float;

// ---- bf16 helpers (bit-level, RN-even) ----
__device__ __forceinline__ float bflo(uint w) {
    union { uint u; float f; } c; c.u = w << 16; return c.f;
}
__device__ __forceinline__ float bfhi(uint w) {
    union { uint u; float f; } c; c.u = w & 0xffff0000u; return c.f;
}
__device__ __forceinline__ uint fp2bf_rn(float f) {
    union { float f; uint u; } c; c.f = f;
    return (c.u + 0x7fffu + ((c.u >> 16) & 1u)) >> 16;
}

// ---------------------------------------------------------------------------
// build: [0, 2*PBLK) edge partition into 64-node bucket record runs;
//        then x -> bf16 + fp8; then W pre-pack.
// rec = src | (dst&63)<<17.  After this kernel bcur[b] = bucket record count.
// ---------------------------------------------------------------------------
__global__ __launch_bounds__(256) void build_kernel(
    const float4* __restrict__ x4, uint2* __restrict__ featb2,
    uint* __restrict__ feat8w,
    const float* __restrict__ Wl, const float* __restrict__ Wr,
    ushort* __restrict__ Wpack,
    const int* __restrict__ srcA, const int* __restrict__ dstA,
    const int* __restrict__ srcB, const int* __restrict__ dstB,
    int* __restrict__ bcurA, int* __restrict__ bcurB,
    uint* __restrict__ ebufA, uint* __restrict__ ebufB) {
    const int blk = blockIdx.x;
    const int t   = threadIdx.x;
    if (blk < 2 * PBLK) {
        __shared__ int h[NBUCK];
        __shared__ int base[NBUCK];
        const int typ = blk >= PBLK;
        const int* src = typ ? srcB : srcA;
        const int* dst = typ ? dstB : dstA;
        int* bc        = typ ? bcurB : bcurA;
        uint* ebuf     = typ ? ebufB : ebufA;
        const int e0 = (blk - (typ ? PBLK : 0)) * EPB;
        for (int j = t; j < NBUCK; j += 256) h[j] = 0;
        __syncthreads();
#pragma unroll
        for (int i = 0; i < EPB / 256; ++i) {
            const int e = e0 + t + i * 256;
            if (e < NE) atomicAdd(&h[dst[e] >> 6], 1);
        }
        __syncthreads();
        for (int j = t; j < NBUCK; j += 256) {
            const int c = h[j];
            base[j] = c ? atomicAdd(&bc[j], c) : 0;
            h[j] = 0;                    // reuse as local cursor
        }
        __syncthreads();
#pragma unroll
        for (int i = 0; i < EPB / 256; ++i) {
            const int e = e0 + t + i * 256;
            if (e < NE) {
                const int d  = dst[e];
                const int bk = d >> 6;
                const int pos = atomicAdd(&h[bk], 1);
                const int off = base[bk] + pos;
                if (off < CAP)
                    ebuf[(size_t)bk * CAP + off] = (uint)src[e] | ((uint)(d & 63) << 17);
            }
        }
    } else if (blk < 2 * PBLK + F2B_BLKS) {
        const int i = (blk - 2 * PBLK) * 256 + t;
        float4 v = x4[i];
        uint2 o;
        o.x = fp2bf_rn(v.x) | (fp2bf_rn(v.y) << 16);
        o.y = fp2bf_rn(v.z) | (fp2bf_rn(v.w) << 16);
        featb2[i] = o;
        int pk = __builtin_amdgcn_cvt_pk_fp8_f32(v.x, v.y, 0, false);
        pk = __builtin_amdgcn_cvt_pk_fp8_f32(v.z, v.w, pk, true);
        feat8w[i] = (uint)pk;
    } else {
        const int i   = (blk - 2 * PBLK - F2B_BLKS) * 256 + t;  // [2][12][128][32]
        const int l   = i / 49152;
        const int rem = i % 49152;
        const int ks  = rem / 4096;
        const int n   = (rem % 4096) / 32;
        const int kk  = rem % 32;
        const int r   = ks * 32 + kk;
        float v;
        if (r < 128)       v = Wl[(((size_t)l * 2 + 0) * 128 + r) * 128 + n];
        else if (r < 256)  v = Wl[(((size_t)l * 2 + 1) * 128 + (r - 128)) * 128 + n];
        else               v = Wr[(((size_t)l * 2 + 0) * 128 + (r - 256)) * 128 + n]
                             + Wr[(((size_t)l * 2 + 1) * 128 + (r - 256)) * 128 + n];
        Wpack[i] = (ushort)fp2bf_rn(v);
    }
}

// ---------------------------------------------------------------------------
// fused: one block per 64-node bucket:
//  (1) stage bucket records in LDS; per-node count/scan/place (in-LDS sort)
//  (1b) counting-rank the 128 lists by length (LPT balance)
//  (2) gather means from FP8 features; cluster cl takes A-rank[cl] and
//      B-rank[63-cl] (balanced totals, no wave divergence); unroll-8;
//      register accumulation -> bf16 means in LDS
//  (3) 64x128 MFMA GEMM over K=384 = [meanA|meanB|self] (bf16)
//      out[i,:] = act( meanA@W0 + meanB@W1 + self@(Wr0+Wr1) + b0+b1 )
// 1024 threads = 16 waves; 64 gather clusters x 16 lanes.
// ---------------------------------------------------------------------------
__global__ __launch_bounds__(1024, 8) void fused_kernel(
    const uint4* __restrict__ feat,      // layer input bf16 [N][16] (self/GEMM)
    const uint2* __restrict__ feat8,     // layer input fp8 [N][16] (gather)
    const uint* __restrict__ ebufA, const uint* __restrict__ ebufB,
    const int* __restrict__ bcntA, const int* __restrict__ bcntB,
    const ushort* __restrict__ Wpack,    // [12][128][32] bf16 for this layer
    const float* __restrict__ bias0, const float* __restrict__ bias1,
    float* __restrict__ outf, ushort* __restrict__ outb,
    uchar* __restrict__ out8, int act) {

    __shared__ uint   mlds[2 * BN * MPITCH];   // bf16 means  (34816 B)
    __shared__ uint   rlds[2][CAP];            // staged records (10240 B)
    __shared__ ushort lidx[2][CAP];            // per-node src lists (5120 B)
    __shared__ int    cnt[128], ex[128], cur[128];
    __shared__ uchar  rankedA[64], rankedB[64];

    const int b = blockIdx.x;
    const int t = threadIdx.x;

    // ---- (1) stage records + per-node sort ----
    if (t < 128) cnt[t] = 0;
    int countA = bcntA[b]; if (countA > CAP) countA = CAP;
    int countB = bcntB[b]; if (countB > CAP) countB = CAP;
    const uint* ebA = ebufA + (size_t)b * CAP;
    const uint* ebB = ebufB + (size_t)b * CAP;
    for (int e = t; e < countA; e += 1024) rlds[0][e] = ebA[e];
    for (int e = t; e < countB; e += 1024) rlds[1][e] = ebB[e];
    __syncthreads();
    for (int e = t; e < countA; e += 1024) atomicAdd(&cnt[rlds[0][e] >> 17], 1);
    for (int e = t; e < countB; e += 1024) atomicAdd(&cnt[64 + (rlds[1][e] >> 17)], 1);
    __syncthreads();
    if (t < 128) ex[t] = cnt[t];
    __syncthreads();
    // two independent 64-wide Hillis-Steele scans (threads 0-63 and 64-127)
    for (int off = 1; off < 64; off <<= 1) {
        int v = 0;
        if (t < 128 && (t & 63) >= off) v = ex[t - off];
        __syncthreads();
        if (t < 128 && (t & 63) >= off) ex[t] += v;
        __syncthreads();
    }
    if (t < 128) { ex[t] -= cnt[t]; cur[t] = ex[t]; }   // exclusive base
    __syncthreads();
    for (int e = t; e < countA; e += 1024) {
        const uint rec = rlds[0][e];
        const int p = atomicAdd(&cur[rec >> 17], 1);
        lidx[0][p] = (ushort)(rec & 0x1FFFFu);
    }
    for (int e = t; e < countB; e += 1024) {
        const uint rec = rlds[1][e];
        const int p = atomicAdd(&cur[64 + (rec >> 17)], 1);
        lidx[1][p] = (ushort)(rec & 0x1FFFFu);
    }
    // ---- (1b) counting rank by list length (desc), per type ----
    if (t < 128) {
        const int typ = t >> 6, i = t & 63;
        const int li = cnt[t];
        const int base = typ * 64;
        int r = 0;
#pragma unroll 8
        for (int j = 0; j < 64; ++j) {
            const int lj = cnt[base + j];
            r += (lj > li) || (lj == li && j < i);
        }
        if (typ == 0) rankedA[r] = (uchar)i; else rankedB[r] = (uchar)i;
    }
    __syncthreads();

    // ---- (2) gather phase: balanced cluster->list mapping, fp8 rows ----
    const int cl = t >> 4, ln = t & 15;
#pragma unroll
    for (int typ = 0; typ < 2; ++typ) {
        const int node = typ ? (int)rankedB[63 - cl] : (int)rankedA[cl];
        const int slot = typ * 64 + node;
        const int beg = ex[slot];
        const int deg = cnt[slot];
        const int fin = beg + deg;
        const ushort* lx = lidx[typ];
        float a[8] = {0.f,0.f,0.f,0.f,0.f,0.f,0.f,0.f};
#define ACC8(w) { \
    auto p0 = __builtin_amdgcn_cvt_pk_f32_fp8((int)(w).x, false); \
    auto p1 = __builtin_amdgcn_cvt_pk_f32_fp8((int)(w).x, true);  \
    auto p2 = __builtin_amdgcn_cvt_pk_f32_fp8((int)(w).y, false); \
    auto p3 = __builtin_amdgcn_cvt_pk_f32_fp8((int)(w).y, true);  \
    a[0]+=p0[0]; a[1]+=p0[1]; a[2]+=p1[0]; a[3]+=p1[1];           \
    a[4]+=p2[0]; a[5]+=p2[1]; a[6]+=p3[0]; a[7]+=p3[1]; }
        int e = beg;
        for (; e + 8 <= fin; e += 8) {
            uint2 w0 = feat8[(size_t)lx[e]     * 16 + ln];
            uint2 w1 = feat8[(size_t)lx[e + 1] * 16 + ln];
            uint2 w2 = feat8[(size_t)lx[e + 2] * 16 + ln];
            uint2 w3 = feat8[(size_t)lx[e + 3] * 16 + ln];
            uint2 w4 = feat8[(size_t)lx[e + 4] * 16 + ln];
            uint2 w5 = feat8[(size_t)lx[e + 5] * 16 + ln];
            uint2 w6 = feat8[(size_t)lx[e + 6] * 16 + ln];
            uint2 w7 = feat8[(size_t)lx[e + 7] * 16 + ln];
            ACC8(w0); ACC8(w1); ACC8(w2); ACC8(w3);
            ACC8(w4); ACC8(w5); ACC8(w6); ACC8(w7);
        }
        if (e + 4 <= fin) {
            uint2 w0 = feat8[(size_t)lx[e]     * 16 + ln];
            uint2 w1 = feat8[(size_t)lx[e + 1] * 16 + ln];
            uint2 w2 = feat8[(size_t)lx[e + 2] * 16 + ln];
            uint2 w3 = feat8[(size_t)lx[e + 3] * 16 + ln];
            ACC8(w0); ACC8(w1); ACC8(w2); ACC8(w3);
            e += 4;
        }
        for (; e < fin; ++e) {
            uint2 w0 = feat8[(size_t)lx[e] * 16 + ln];
            ACC8(w0);
        }
#undef ACC8
        const float invd = 1.0f / fmaxf((float)deg, 1.0f);
        uint4 o;
        o.x = fp2bf_rn(a[0] * invd) | (fp2bf_rn(a[1] * invd) << 16);
        o.y = fp2bf_rn(a[2] * invd) | (fp2bf_rn(a[3] * invd) << 16);
        o.z = fp2bf_rn(a[4] * invd) | (fp2bf_rn(a[5] * invd) << 16);
        o.w = fp2bf_rn(a[6] * invd) | (fp2bf_rn(a[7] * invd) << 16);
        *reinterpret_cast<uint4*>(&mlds[(typ * BN + node) * MPITCH + ln * 4]) = o;
    }
    __syncthreads();

    // ---- (3) GEMM phase: 64 rows x 128 cols, K = 12 x 32, 16 waves ----
    const int wid = t >> 6, wl = t & 63;
    const int mrow = wl & 15, g = wl >> 4;
    const int mt   = wid >> 2;             // 0..3
    const int ntp  = (wid & 3) * 2;        // 0,2,4,6
    const int arow = mt * 16 + mrow;       // 0..63

    f32x4 acc0 = (f32x4){0.f, 0.f, 0.f, 0.f};
    f32x4 acc1 = (f32x4){0.f, 0.f, 0.f, 0.f};
#pragma unroll
    for (int ks = 0; ks < 12; ++ks) {
        union { uint4 u; bf16x8 v; } av;
        if (ks < 8) {
            av.u = *reinterpret_cast<const uint4*>(
                &mlds[((ks >> 2) * BN + arow) * MPITCH + (ks & 3) * 16 + g * 4]);
        } else {
            int srow = b * BN + arow;
            if (srow >= N_NODES) srow = N_NODES - 1;
            av.u = feat[(size_t)srow * 16 + (ks & 3) * 4 + g];
        }
        const ushort* Wk = Wpack + (size_t)ks * 128 * 32;
        union { uint4 u; bf16x8 v; } bv0, bv1;
        bv0.u = *reinterpret_cast<const uint4*>(Wk + ((ntp * 16 + mrow) * 32 + g * 8));
        bv1.u = *reinterpret_cast<const uint4*>(Wk + (((ntp + 1) * 16 + mrow) * 32 + g * 8));
        acc0 = __builtin_amdgcn_mfma_f32_16x16x32_bf16(av.v, bv0.v, acc0, 0, 0, 0);
        acc1 = __builtin_amdgcn_mfma_f32_16x16x32_bf16(av.v, bv1.v, acc1, 0, 0, 0);
    }

    // ---- epilogue ----
#pragma unroll
    for (int q = 0; q < 2; ++q) {
        const f32x4 av = q ? acc1 : acc0;
        const int col = (ntp + q) * 16 + mrow;
        const float bias = bias0[col] + bias1[col];
#pragma unroll
        for (int r = 0; r < 4; ++r) {
            const int row = b * BN + mt * 16 + g * 4 + r;
            if (row < N_NODES) {
                const float v = av[r] + bias;
                if (act) {
                    outf[(size_t)row * D + col] = 1.0f / (1.0f + expf(-v));
                } else {
                    outb[(size_t)row * D + col] = (ushort)fp2bf_rn(v);
                    const int pk = __builtin_amdgcn_cvt_pk_fp8_f32(v, v, 0, false);
                    out8[(size_t)row * D + col] = (uchar)(pk & 0xFF);
                }
            }
        }
    }
}

// ---------------------------------------------------------------------------
extern "C" void kernel_launch(void* const* d_in, const int* in_sizes, int n_in,
                              void* d_out, int out_size, void* d_ws, size_t ws_size,
                              hipStream_t stream) {
    const float* x    = (const float*)d_in[0];
    const int*   ei_a = (const int*)d_in[2];
    const int*   ei_b = (const int*)d_in[3];
    const float* Wl   = (const float*)d_in[4];
    const float* bl   = (const float*)d_in[5];
    const float* Wr   = (const float*)d_in[6];
    float* out = (float*)d_out;

    // ---- workspace (~47 MB) ----
    ushort* featb = (ushort*)d_ws;                           // [N][128] bf16
    ushort* feat2 = featb + (size_t)N_NODES * D;             // [N][128] bf16
    uchar* feat8  = (uchar*)(feat2 + (size_t)N_NODES * D);   // [N][128] fp8
    uchar* feat28 = feat8 + (size_t)N_NODES * D;             // [N][128] fp8
    uint* ebufA = (uint*)(feat28 + (size_t)N_NODES * D);     // NBUCK*CAP
    uint* ebufB = ebufA + (size_t)NBUCK * CAP;
    int* bcurA  = (int*)(ebufB + (size_t)NBUCK * CAP);       // NBUCK
    int* bcurB  = bcurA + NBUCK;
    ushort* Wpack = (ushort*)(((size_t)(bcurB + NBUCK) + 63) & ~(size_t)63);

    const int* srcA = ei_a;
    const int* dstA = ei_a + NE;
    const int* srcB = ei_b;
    const int* dstB = ei_b + NE;

    hipMemsetAsync(bcurA, 0, 2ull * NBUCK * sizeof(int), stream);
    build_kernel<<<2 * PBLK + F2B_BLKS + WPREP_BLKS, 256, 0, stream>>>(
        (const float4*)x, (uint2*)featb, (uint*)feat8, Wl, Wr, Wpack,
        srcA, dstA, srcB, dstB, bcurA, bcurB, ebufA, ebufB);

    fused_kernel<<<NBUCK, 1024, 0, stream>>>(
        (const uint4*)featb, (const uint2*)feat8, ebufA, ebufB, bcurA, bcurB,
        Wpack, bl + 0 * D, bl + 1 * D, nullptr, feat2, feat28, 0);
    fused_kernel<<<NBUCK, 1024, 0, stream>>>(
        (const uint4*)feat2, (const uint2*)feat28, ebufA, ebufB, bcurA, bcurB,
        Wpack + (size_t)12 * 128 * 32, bl + 2 * D, bl + 3 * D, out, nullptr, nullptr, 1);
}